// Round 1
// baseline (111.917 us; speedup 1.0000x reference)
//
#include <hip/hip_runtime.h>
#include <math.h>

#define NB 128      // batches
#define TC 128      // subsampled points per batch
#define DD 512      // feature dim
#define TSTR 16     // subsample stride (2048/128)
#define KT 32       // K tile
#define NTILE (DD/KT)
#define XSTR 36     // padded LDS row stride (words) -> conflict-free b128 reads
#define NTRIP 32

__global__ __launch_bounds__(256) void topo_main(
    const float* __restrict__ latent,   // [128][2048][512]
    const float* __restrict__ thr,      // [1]
    const int*   __restrict__ trip,     // [128][32][3]
    float* __restrict__ partial)        // [2*NB]
{
  const int b   = blockIdx.x;
  const int tid = threadIdx.x;
  const int tx  = tid & 15;   // j-group
  const int ty  = tid >> 4;   // i-group

  __shared__ __align__(16) float xt[2][TC][XSTR];  // 36.9 KB
  __shared__ float dmat[TC][TC];                   // 64 KB
  __shared__ float sqn[TC];
  __shared__ float wred[4];

  const float* xb = latent + (size_t)b * (2048 * 512);

  float acc[8][8];
#pragma unroll
  for (int r = 0; r < 8; ++r)
#pragma unroll
    for (int c = 0; c < 8; ++c) acc[r][c] = 0.f;

  // stage tile 0: xt[0][row][k] = xb[row*16*512 + k], k in [0,32)
#pragma unroll
  for (int q = 0; q < 4; ++q) {
    int f = tid + 256 * q;          // 1024 float4 per tile
    int row = f >> 3, k4 = f & 7;
    float4 v = *reinterpret_cast<const float4*>(xb + (size_t)row * (TSTR * DD) + k4 * 4);
    *reinterpret_cast<float4*>(&xt[0][row][k4 * 4]) = v;
  }

  for (int t = 0; t < NTILE; ++t) {
    __syncthreads();                 // tile t staged; prev compute done
    const int cur = t & 1;
    if (t + 1 < NTILE) {
#pragma unroll
      for (int q = 0; q < 4; ++q) {
        int f = tid + 256 * q;
        int row = f >> 3, k4 = f & 7;
        float4 v = *reinterpret_cast<const float4*>(
            xb + (size_t)row * (TSTR * DD) + (t + 1) * KT + k4 * 4);
        *reinterpret_cast<float4*>(&xt[cur ^ 1][row][k4 * 4]) = v;
      }
    }
    // Gram accumulate: thread owns rows I(r)=ty+16r, cols J(c)=tx+16c
#pragma unroll
    for (int k4 = 0; k4 < KT / 4; ++k4) {
      float4 xi[8];
#pragma unroll
      for (int r = 0; r < 8; ++r)
        xi[r] = *reinterpret_cast<const float4*>(&xt[cur][ty + 16 * r][k4 * 4]);
#pragma unroll
      for (int c = 0; c < 8; ++c) {
        float4 xj = *reinterpret_cast<const float4*>(&xt[cur][tx + 16 * c][k4 * 4]);
#pragma unroll
        for (int r = 0; r < 8; ++r) {
          acc[r][c] += xi[r].x * xj.x + xi[r].y * xj.y +
                       xi[r].z * xj.z + xi[r].w * xj.w;
        }
      }
    }
  }
  __syncthreads();

  // squared norms = diagonal of Gram (owned by threads tx==ty)
  if (tx == ty) {
#pragma unroll
    for (int r = 0; r < 8; ++r) sqn[tx + 16 * r] = acc[r][r];
  }
  __syncthreads();

  const float threshold = fabsf(thr[0]) + 0.1f;
  float psum = 0.f;
#pragma unroll
  for (int r = 0; r < 8; ++r) {
    const int i = ty + 16 * r;
    const float si = sqn[i];
#pragma unroll
    for (int c = 0; c < 8; ++c) {
      const int j = tx + 16 * c;
      float sq = si + sqn[j] - 2.f * acc[r][c];
      sq = fmaxf(sq, 0.f);
      float d = sqrtf(sq);
      dmat[i][j] = d;
      if (i != j) psum += 1.f / (1.f + __expf(d - threshold));  // sigmoid(thr-d)
    }
  }

  // block reduction of psum
#pragma unroll
  for (int off = 32; off; off >>= 1) psum += __shfl_down(psum, off, 64);
  if ((tid & 63) == 0) wred[tid >> 6] = psum;
  __syncthreads();   // also fences dmat writes for triplet gather

  // triplets: 32 per batch, handled by wave 0
  if (tid < 64) {
    float h = 0.f;
    if (tid < NTRIP) {
      const int* tp = trip + ((size_t)b * NTRIP + tid) * 3;
      int i0 = tp[0], i1 = tp[1], i2 = tp[2];
      float e0 = dmat[i0][i1], e1 = dmat[i0][i2], e2 = dmat[i1][i2];
      float m  = (e0 + e1 + e2) * (1.f / 3.f);
      float d0 = e0 - m, d1 = e1 - m, d2 = e2 - m;
      float v  = (d0 * d0 + d1 * d1 + d2 * d2) * 0.5f;  // ddof=1
      h = __expf(-v);
    }
#pragma unroll
    for (int off = 32; off; off >>= 1) h += __shfl_down(h, off, 64);
    if (tid == 0) {
      float conn = wred[0] + wred[1] + wred[2] + wred[3];
      partial[b]      = 1.f - conn / 16256.0f;   // Tc*(Tc-1)+1e-8
      partial[NB + b] = h * (1.f / NTRIP);
    }
  }
}

__global__ void topo_final(const float* __restrict__ partial, float* __restrict__ out)
{
  const int t = threadIdx.x;  // 128 threads
  float v = partial[t] + 0.5f * partial[NB + t];
#pragma unroll
  for (int off = 32; off; off >>= 1) v += __shfl_down(v, off, 64);
  __shared__ float s2[2];
  if ((t & 63) == 0) s2[t >> 6] = v;
  __syncthreads();
  if (t == 0) out[0] = (s2[0] + s2[1]) * (1.f / NB);
}

extern "C" void kernel_launch(void* const* d_in, const int* in_sizes, int n_in,
                              void* d_out, int out_size, void* d_ws, size_t ws_size,
                              hipStream_t stream) {
  const float* latent = (const float*)d_in[0];
  const float* thr    = (const float*)d_in[1];
  const int*   trip   = (const int*)d_in[2];
  float* partial = (float*)d_ws;   // 256 floats

  topo_main<<<NB, 256, 0, stream>>>(latent, thr, trip, partial);
  topo_final<<<1, 128, 0, stream>>>(partial, (float*)d_out);
}

// Round 2
// 74.646 us; speedup vs baseline: 1.4993x; 1.4993x over previous
//
#include <hip/hip_runtime.h>
#include <math.h>

#define NB 128      // batches
#define TC 128      // subsampled points per batch
#define DD 512      // feature dim
#define TSTR 16     // subsample stride (2048/128)
#define KSPLIT 2
#define KHALF (DD/KSPLIT)   // 256 dims per gram block
#define KT 32               // K tile staged in LDS
#define NT (KHALF/KT)       // 8 tiles
#define XSTR 36             // padded LDS row stride (words): conflict-free b128
#define NTRIP 32

// K1: partial Gram over one K-half. grid = 256 blocks (batch*2 + ksplit).
// LDS only 36 KB (no dmat) -> all 256 CUs busy, 4 waves/CU.
__global__ __launch_bounds__(256) void gram_k(
    const float* __restrict__ latent,   // [128][2048][512]
    float* __restrict__ gpart)          // [256][128][128]
{
  const int blk = blockIdx.x;
  const int b   = blk >> 1;
  const int s   = blk & 1;
  const int tid = threadIdx.x;
  const int tx  = tid & 15;   // j-group
  const int ty  = tid >> 4;   // i-group

  __shared__ __align__(16) float xt[2][TC][XSTR];  // 36.9 KB

  const float* xb = latent + (size_t)b * (2048 * 512) + s * KHALF;

  float acc[8][8];
#pragma unroll
  for (int r = 0; r < 8; ++r)
#pragma unroll
    for (int c = 0; c < 8; ++c) acc[r][c] = 0.f;

  // stage tile 0: rows 0..127 (subsample stride 16 rows => 8192 floats), k 0..31
#pragma unroll
  for (int q = 0; q < 4; ++q) {
    int f = tid + 256 * q;          // 1024 float4 per tile
    int row = f >> 3, k4 = f & 7;
    float4 v = *reinterpret_cast<const float4*>(xb + (size_t)row * (TSTR * DD) + k4 * 4);
    *reinterpret_cast<float4*>(&xt[0][row][k4 * 4]) = v;
  }

  for (int t = 0; t < NT; ++t) {
    __syncthreads();
    const int cur = t & 1;
    if (t + 1 < NT) {
#pragma unroll
      for (int q = 0; q < 4; ++q) {
        int f = tid + 256 * q;
        int row = f >> 3, k4 = f & 7;
        float4 v = *reinterpret_cast<const float4*>(
            xb + (size_t)row * (TSTR * DD) + (t + 1) * KT + k4 * 4);
        *reinterpret_cast<float4*>(&xt[cur ^ 1][row][k4 * 4]) = v;
      }
    }
#pragma unroll
    for (int k4 = 0; k4 < KT / 4; ++k4) {
      float4 xi[8];
#pragma unroll
      for (int r = 0; r < 8; ++r)
        xi[r] = *reinterpret_cast<const float4*>(&xt[cur][ty + 16 * r][k4 * 4]);
#pragma unroll
      for (int c = 0; c < 8; ++c) {
        float4 xj = *reinterpret_cast<const float4*>(&xt[cur][tx + 16 * c][k4 * 4]);
#pragma unroll
        for (int r = 0; r < 8; ++r) {
          acc[r][c] += xi[r].x * xj.x + xi[r].y * xj.y +
                       xi[r].z * xj.z + xi[r].w * xj.w;
        }
      }
    }
  }

  float* gp = gpart + (size_t)blk * (TC * TC);
#pragma unroll
  for (int r = 0; r < 8; ++r)
#pragma unroll
    for (int c = 0; c < 8; ++c)
      gp[(ty + 16 * r) * TC + (tx + 16 * c)] = acc[r][c];
}

// K2: per-batch epilogue. d from summed Gram halves; sigmoid sum; triplets.
__global__ __launch_bounds__(256) void epi_k(
    const float* __restrict__ gpart,
    const float* __restrict__ thr,
    const int*   __restrict__ trip,
    float* __restrict__ partial)        // [2*NB]
{
  const int b   = blockIdx.x;
  const int tid = threadIdx.x;

  __shared__ float dmat[TC][TC];
  __shared__ float sqn[TC];
  __shared__ float wred[4];

  const float* g0 = gpart + (size_t)(2 * b) * (TC * TC);
  const float* g1 = gpart + (size_t)(2 * b + 1) * (TC * TC);

  if (tid < TC) sqn[tid] = g0[tid * (TC + 1)] + g1[tid * (TC + 1)];
  __syncthreads();

  const float threshold = fabsf(thr[0]) + 0.1f;
  float psum = 0.f;
#pragma unroll
  for (int q = 0; q < 16; ++q) {
    int f = tid + 256 * q;            // 4096 float4 per batch
    int i = f >> 5, j0 = (f & 31) * 4;
    float4 a = *reinterpret_cast<const float4*>(g0 + i * TC + j0);
    float4 c = *reinterpret_cast<const float4*>(g1 + i * TC + j0);
    float4 sj = *reinterpret_cast<const float4*>(&sqn[j0]);
    const float si = sqn[i];
    float4 dv;
    {
      float sq = fmaxf(si + sj.x - 2.f * (a.x + c.x), 0.f);
      dv.x = sqrtf(sq);
      if (i != j0 + 0) psum += 1.f / (1.f + __expf(dv.x - threshold));
      sq = fmaxf(si + sj.y - 2.f * (a.y + c.y), 0.f);
      dv.y = sqrtf(sq);
      if (i != j0 + 1) psum += 1.f / (1.f + __expf(dv.y - threshold));
      sq = fmaxf(si + sj.z - 2.f * (a.z + c.z), 0.f);
      dv.z = sqrtf(sq);
      if (i != j0 + 2) psum += 1.f / (1.f + __expf(dv.z - threshold));
      sq = fmaxf(si + sj.w - 2.f * (a.w + c.w), 0.f);
      dv.w = sqrtf(sq);
      if (i != j0 + 3) psum += 1.f / (1.f + __expf(dv.w - threshold));
    }
    *reinterpret_cast<float4*>(&dmat[i][j0]) = dv;
  }

#pragma unroll
  for (int off = 32; off; off >>= 1) psum += __shfl_down(psum, off, 64);
  if ((tid & 63) == 0) wred[tid >> 6] = psum;
  __syncthreads();   // also fences dmat for triplet gather

  if (tid < 64) {
    float h = 0.f;
    if (tid < NTRIP) {
      const int* tp = trip + ((size_t)b * NTRIP + tid) * 3;
      int i0 = tp[0], i1 = tp[1], i2 = tp[2];
      float e0 = dmat[i0][i1], e1 = dmat[i0][i2], e2 = dmat[i1][i2];
      float m  = (e0 + e1 + e2) * (1.f / 3.f);
      float d0 = e0 - m, d1 = e1 - m, d2 = e2 - m;
      float v  = (d0 * d0 + d1 * d1 + d2 * d2) * 0.5f;  // ddof=1
      h = __expf(-v);
    }
#pragma unroll
    for (int off = 32; off; off >>= 1) h += __shfl_down(h, off, 64);
    if (tid == 0) {
      float conn = wred[0] + wred[1] + wred[2] + wred[3];
      partial[b]      = 1.f - conn / 16256.0f;   // Tc*(Tc-1)+1e-8
      partial[NB + b] = h * (1.f / NTRIP);
    }
  }
}

__global__ void topo_final(const float* __restrict__ partial, float* __restrict__ out)
{
  const int t = threadIdx.x;  // 128 threads
  float v = partial[t] + 0.5f * partial[NB + t];
#pragma unroll
  for (int off = 32; off; off >>= 1) v += __shfl_down(v, off, 64);
  __shared__ float s2[2];
  if ((t & 63) == 0) s2[t >> 6] = v;
  __syncthreads();
  if (t == 0) out[0] = (s2[0] + s2[1]) * (1.f / NB);
}

extern "C" void kernel_launch(void* const* d_in, const int* in_sizes, int n_in,
                              void* d_out, int out_size, void* d_ws, size_t ws_size,
                              hipStream_t stream) {
  const float* latent = (const float*)d_in[0];
  const float* thr    = (const float*)d_in[1];
  const int*   trip   = (const int*)d_in[2];

  float* gpart   = (float*)d_ws;                       // 256*16384 floats = 16 MB
  float* partial = gpart + (size_t)256 * TC * TC;      // 256 floats

  gram_k<<<NB * KSPLIT, 256, 0, stream>>>(latent, gpart);
  epi_k<<<NB, 256, 0, stream>>>(gpart, thr, trip, partial);
  topo_final<<<1, 128, 0, stream>>>(partial, (float*)d_out);
}

// Round 3
// 18.727 us; speedup vs baseline: 5.9762x; 3.9859x over previous
//
#include <hip/hip_runtime.h>
#include <math.h>

#define NB 128      // batches
#define TC 128      // subsampled points per batch
#define DD 512      // feature dim
#define TSTR 16     // subsample stride (2048/128)
#define KT 64       // K-tile (floats) staged per iteration
#define NT (DD/KT)  // 8 tiles
#define XP 72       // bf16 LDS row stride (64 + 8 pad) -> conflict-free b128
#define DST 132     // dmat row stride (floats): lanes 16-31 shift banks by 16
#define NTRIP 32

typedef __attribute__((ext_vector_type(8))) short bf16x8;
typedef __attribute__((ext_vector_type(8))) unsigned short u16x8;
typedef __attribute__((ext_vector_type(4))) float f32x4;

__device__ __forceinline__ unsigned short f2bf(float f) {
  // round-to-nearest-even bf16 (inputs are finite normals)
  unsigned int u = __float_as_uint(f);
  return (unsigned short)((u + 0x7fffu + ((u >> 16) & 1u)) >> 16);
}

// One block per batch: stage bf16 K-tiles (double-buffered), MFMA Gram,
// fused distance/sigmoid/triplet epilogue. 1024 threads = 16 waves (4x4 grid).
__global__ __launch_bounds__(1024) void topo_fused(
    const float* __restrict__ latent,   // [128][2048][512]
    const float* __restrict__ thr,      // [1]
    const int*   __restrict__ trip,     // [128][32][3]
    float* __restrict__ partial)        // [2*NB]
{
  const int b    = blockIdx.x;
  const int tid  = threadIdx.x;
  const int lane = tid & 63;
  const int wid  = tid >> 6;          // 0..15
  const int wrow = (wid >> 2) * 32;   // wave tile 32x32
  const int wcol = (wid & 3) * 32;

  __shared__ __align__(16) unsigned short xt[2][TC][XP];  // 36.9 KB
  __shared__ float dmat[TC][DST];                         // 67.6 KB
  __shared__ float sqn[TC];
  __shared__ float wred[16];

  const float* xb = latent + (size_t)b * (2048 * 512);

  // staging: thread t -> row t>>3 (128 rows), k-chunk (t&7)*8 (64 floats/row)
  const int srow = tid >> 3;
  const int skc  = (tid & 7) * 8;
  const float* sp = xb + (size_t)srow * (TSTR * DD) + skc;

  f32x4 acc[2][2];
#pragma unroll
  for (int i = 0; i < 2; ++i)
#pragma unroll
    for (int j = 0; j < 2; ++j)
#pragma unroll
      for (int r = 0; r < 4; ++r) acc[i][j][r] = 0.f;

  // prologue: stage tile 0
  {
    float4 pa = *reinterpret_cast<const float4*>(sp);
    float4 pb = *reinterpret_cast<const float4*>(sp + 4);
    u16x8 w;
    w[0]=f2bf(pa.x); w[1]=f2bf(pa.y); w[2]=f2bf(pa.z); w[3]=f2bf(pa.w);
    w[4]=f2bf(pb.x); w[5]=f2bf(pb.y); w[6]=f2bf(pb.z); w[7]=f2bf(pb.w);
    *reinterpret_cast<u16x8*>(&xt[0][srow][skc]) = w;
  }

  const int r0  = wrow + (lane & 15);
  const int c0  = wcol + (lane & 15);
  const int kk0 = (lane >> 4) << 3;

  for (int t = 0; t < NT; ++t) {
    float4 pa, pb;
    const bool pf = (t + 1 < NT);
    if (pf) {   // issue next-tile global loads before the barrier (overlap HBM)
      pa = *reinterpret_cast<const float4*>(sp + (t + 1) * KT);
      pb = *reinterpret_cast<const float4*>(sp + (t + 1) * KT + 4);
    }
    __syncthreads();   // tile t writes visible; buf (t+1)&1 free to overwrite
    if (pf) {
      u16x8 w;
      w[0]=f2bf(pa.x); w[1]=f2bf(pa.y); w[2]=f2bf(pa.z); w[3]=f2bf(pa.w);
      w[4]=f2bf(pb.x); w[5]=f2bf(pb.y); w[6]=f2bf(pb.z); w[7]=f2bf(pb.w);
      *reinterpret_cast<u16x8*>(&xt[(t + 1) & 1][srow][skc]) = w;
    }
    const int cur = t & 1;
#pragma unroll
    for (int sub = 0; sub < 2; ++sub) {
      const int kk = sub * 32 + kk0;
      bf16x8 a0 = *reinterpret_cast<const bf16x8*>(&xt[cur][r0][kk]);
      bf16x8 a1 = *reinterpret_cast<const bf16x8*>(&xt[cur][r0 + 16][kk]);
      bf16x8 b0 = *reinterpret_cast<const bf16x8*>(&xt[cur][c0][kk]);
      bf16x8 b1 = *reinterpret_cast<const bf16x8*>(&xt[cur][c0 + 16][kk]);
      acc[0][0] = __builtin_amdgcn_mfma_f32_16x16x32_bf16(a0, b0, acc[0][0], 0, 0, 0);
      acc[0][1] = __builtin_amdgcn_mfma_f32_16x16x32_bf16(a0, b1, acc[0][1], 0, 0, 0);
      acc[1][0] = __builtin_amdgcn_mfma_f32_16x16x32_bf16(a1, b0, acc[1][0], 0, 0, 0);
      acc[1][1] = __builtin_amdgcn_mfma_f32_16x16x32_bf16(a1, b1, acc[1][1], 0, 0, 0);
    }
  }

  // diagonal -> sqn (C/D layout: col=lane&15, row=(lane>>4)*4+reg  [m89])
  const int rbase = (lane >> 4) << 2;
  const int cidx  = lane & 15;
#pragma unroll
  for (int fr = 0; fr < 2; ++fr)
#pragma unroll
    for (int fc = 0; fc < 2; ++fc)
#pragma unroll
      for (int reg = 0; reg < 4; ++reg) {
        int grow = wrow + fr * 16 + rbase + reg;
        int gcol = wcol + fc * 16 + cidx;
        if (grow == gcol) sqn[grow] = acc[fr][fc][reg];
      }
  __syncthreads();

  const float thv = fabsf(thr[0]) + 0.1f;
  float psum = 0.f;
#pragma unroll
  for (int fr = 0; fr < 2; ++fr)
#pragma unroll
    for (int fc = 0; fc < 2; ++fc)
#pragma unroll
      for (int reg = 0; reg < 4; ++reg) {
        int grow = wrow + fr * 16 + rbase + reg;
        int gcol = wcol + fc * 16 + cidx;
        float g  = acc[fr][fc][reg];
        float sq = fmaxf(sqn[grow] + sqn[gcol] - 2.f * g, 0.f);
        float d  = sqrtf(sq);
        dmat[grow][gcol] = d;
        if (grow != gcol) psum += 1.f / (1.f + __expf(d - thv));
      }

#pragma unroll
  for (int off = 32; off; off >>= 1) psum += __shfl_down(psum, off, 64);
  if (lane == 0) wred[wid] = psum;
  __syncthreads();   // fences dmat for the triplet gather too

  if (wid == 0) {
    float h = 0.f;
    if (lane < NTRIP) {
      const int* tp = trip + ((size_t)b * NTRIP + lane) * 3;
      int i0 = tp[0], i1 = tp[1], i2 = tp[2];
      float e0 = dmat[i0][i1], e1 = dmat[i0][i2], e2 = dmat[i1][i2];
      float m  = (e0 + e1 + e2) * (1.f / 3.f);
      float d0 = e0 - m, d1 = e1 - m, d2 = e2 - m;
      float v  = (d0 * d0 + d1 * d1 + d2 * d2) * 0.5f;  // ddof=1
      h = __expf(-v);
    }
#pragma unroll
    for (int off = 32; off; off >>= 1) h += __shfl_down(h, off, 64);
    if (lane == 0) {
      float conn = 0.f;
#pragma unroll
      for (int w = 0; w < 16; ++w) conn += wred[w];
      partial[b]      = 1.f - conn / 16256.0f;   // Tc*(Tc-1)+1e-8
      partial[NB + b] = h * (1.f / NTRIP);
    }
  }
}

__global__ void topo_final(const float* __restrict__ partial, float* __restrict__ out)
{
  const int t = threadIdx.x;  // 128 threads
  float v = partial[t] + 0.5f * partial[NB + t];
#pragma unroll
  for (int off = 32; off; off >>= 1) v += __shfl_down(v, off, 64);
  __shared__ float s2[2];
  if ((t & 63) == 0) s2[t >> 6] = v;
  __syncthreads();
  if (t == 0) out[0] = (s2[0] + s2[1]) * (1.f / NB);
}

extern "C" void kernel_launch(void* const* d_in, const int* in_sizes, int n_in,
                              void* d_out, int out_size, void* d_ws, size_t ws_size,
                              hipStream_t stream) {
  const float* latent = (const float*)d_in[0];
  const float* thr    = (const float*)d_in[1];
  const int*   trip   = (const int*)d_in[2];
  float* partial = (float*)d_ws;   // 256 floats

  topo_fused<<<NB, 1024, 0, stream>>>(latent, thr, trip, partial);
  topo_final<<<1, 128, 0, stream>>>(partial, (float*)d_out);
}